// Round 9
// baseline (400.890 us; speedup 1.0000x reference)
//
#include <hip/hip_runtime.h>
#include <stdint.h>

static constexpr int HIN = 256, WIN = 256, HO = 254, WOUT = 254, NB = 8;
static constexpr int PLANE = HO * WOUT;       // 64516
static constexpr int PIX = NB * PLANE;        // 516128

// Ring connectivity: prev atom j feeds next atoms (2j..2j+3) mod a_next.
// Morton-spread mask (j -> bit 2j), duplicate to (2j,2j+1), OR rotate-left-2.
__device__ __forceinline__ uint64_t spread_pairs(uint64_t mask, int a_next) {
  uint64_t s = mask;
  s = (s | (s << 16)) & 0x0000FFFF0000FFFFull;
  s = (s | (s << 8))  & 0x00FF00FF00FF00FFull;
  s = (s | (s << 4))  & 0x0F0F0F0F0F0F0F0Full;
  s = (s | (s << 2))  & 0x3333333333333333ull;
  s = (s | (s << 1))  & 0x5555555555555555ull;
  uint64_t pair = s | (s << 1);
  uint64_t lim = (a_next >= 64) ? ~0ull : ((1ull << a_next) - 1ull);
  uint64_t rot = ((pair << 2) | (pair >> (a_next - 2))) & lim;
  return (pair | rot) & lim;
}

// One level. Conv numerics (validated round 7): single f32 accumulator from 0,
// sequential __fmaf_rn over the patch in (ky, kx, c) order — channels
// innermost (NHWC/HWIO im2col+sgemm mirror) — bias added last, separate add.
// Selection: jax top_k semantics — exactly K kept, ties at the boundary
// broken toward LOWEST channel index.
template<int N, int K, bool GATE>
__device__ __forceinline__ uint64_t do_level(const float (&px)[27],
    const float* __restrict__ w, const float* __restrict__ b,
    int ch0, uint64_t allow, float* __restrict__ out, size_t out_base) {
  float act[N];
#pragma unroll
  for (int j = 0; j < N; ++j) {
    const float* wp = w + (size_t)(ch0 + j) * 27;   // layout (c,ky,kx) per atom
    float acc = 0.0f;
#pragma unroll
    for (int ky = 0; ky < 3; ++ky)
#pragma unroll
      for (int kx = 0; kx < 3; ++kx)
#pragma unroll
        for (int c = 0; c < 3; ++c) {
          int t = c * 9 + ky * 3 + kx;              // source layout index
          acc = __fmaf_rn(px[t], wp[t], acc);       // (ky,kx,c)-ordered FMA chain
        }
    acc = __fadd_rn(acc, b[ch0 + j]);               // bias after conv
    if (GATE) acc = ((allow >> j) & 1ull) ? acc : 0.0f;
    act[j] = acc;
  }

  // m = K-th largest |act| with multiplicity; base = #{ |a| > m }.
  float m = __builtin_inff();
  int cnt = 0, base = 0;
#pragma unroll
  for (int pass = 0; pass < K; ++pass) {
    float mm = -1.0f;
#pragma unroll
    for (int j = 0; j < N; ++j) {
      float aj = fabsf(act[j]);
      mm = (aj < m && aj > mm) ? aj : mm;
    }
    int c = 0;
#pragma unroll
    for (int j = 0; j < N; ++j) c += (fabsf(act[j]) == mm) ? 1 : 0;
    bool active = (cnt < K);
    base = active ? cnt : base;
    m = active ? mm : m;
    cnt = active ? (cnt + c) : cnt;
  }
  int quota = K - base;   // boundary-tied survivors, lowest index first

  uint64_t msk = 0;
#pragma unroll
  for (int j = 0; j < N; ++j) {
    float aj = fabsf(act[j]);
    bool eq = (aj == m);
    bool keep = (aj > m) || (eq && quota > 0);
    quota -= eq ? 1 : 0;
    float v = keep ? act[j] : 0.0f;
    out[out_base + (size_t)(ch0 + j) * PLANE] = v;
    msk |= (v != 0.0f) ? (1ull << j) : 0ull;
  }
  return msk;
}

__global__ __launch_bounds__(256)
void hrtk_main(const float* __restrict__ x, const float* __restrict__ w,
               const float* __restrict__ b, float* __restrict__ out) {
  int p = blockIdx.x * blockDim.x + threadIdx.x;
  if (p >= PIX) return;
  int bi = p / PLANE;
  int r  = p % PLANE;
  int h  = r / WOUT;
  int wc = r % WOUT;

  float px[27];
  const float* xb = x + (size_t)bi * 3 * HIN * WIN;
#pragma unroll
  for (int c = 0; c < 3; ++c)
#pragma unroll
    for (int dy = 0; dy < 3; ++dy)
#pragma unroll
      for (int dx = 0; dx < 3; ++dx)
        px[c * 9 + dy * 3 + dx] =
            xb[c * HIN * WIN + (size_t)(h + dy) * WIN + (wc + dx)];

  size_t out_base = (size_t)bi * 120 * PLANE + (size_t)h * WOUT + wc;

  uint64_t m0 = do_level<8, 2, false>(px, w, b, 0, 0, out, out_base);
  uint64_t a1 = spread_pairs(m0, 16);
  uint64_t m1 = do_level<16, 4, true>(px, w, b, 8, a1, out, out_base);
  uint64_t a2 = spread_pairs(m1, 32);
  uint64_t m2 = do_level<32, 8, true>(px, w, b, 24, a2, out, out_base);
  uint64_t a3 = spread_pairs(m2, 64);
  (void)do_level<64, 16, true>(px, w, b, 56, a3, out, out_base);
}

extern "C" void kernel_launch(void* const* d_in, const int* in_sizes, int n_in,
                              void* d_out, int out_size, void* d_ws, size_t ws_size,
                              hipStream_t stream) {
  const float* x = (const float*)d_in[0];
  const float* w = (const float*)d_in[1];
  const float* b = (const float*)d_in[2];
  float* out = (float*)d_out;
  dim3 blk(256), grid((PIX + 255) / 256);
  hrtk_main<<<grid, blk, 0, stream>>>(x, w, b, out);
}